// Round 18
// baseline (449.315 us; speedup 1.0000x reference)
//
#include <hip/hip_runtime.h>
#include <hip/hip_bf16.h>
#include <stdint.h>

// TreeLSTM fused, round 18: R17 with biases moved to LDS to shave 16 VGPRs.
// Theory: per-SIMD VGPR pool ~= 512 minus a small reserve, so 4 waves x 128
// regs never co-schedule (every VGPR=128 round: occ 23%; R13 @ VGPR=64: 47%).
// Target VGPR <= 120 so 2 blocks/CU (16 waves) fit. Bias reads become
// lgkmcnt ds_reads -> all audited vmcnt immediates unchanged.

typedef __attribute__((ext_vector_type(8))) short bf16x8;
typedef __attribute__((ext_vector_type(4))) float f4v;

#define N_ROWS 200000
#define TILES 12500     // N_ROWS / 16
#define XSTR 258        // LDS row stride in floats (256 + 2) -> 0 conflicts (R14)
#define VMW(N) asm volatile("s_waitcnt vmcnt(" #N ")" ::: "memory")
#define LKW0() asm volatile("s_waitcnt lgkmcnt(0)" ::: "memory")
#define SBR() __builtin_amdgcn_sched_barrier(0)

__device__ __forceinline__ bf16x8 pack8(f4v a, f4v b) {
    union { __hip_bfloat162 h2[4]; bf16x8 v; } u;
    u.h2[0] = __float22bfloat162_rn(make_float2(a.x, a.y));
    u.h2[1] = __float22bfloat162_rn(make_float2(a.z, a.w));
    u.h2[2] = __float22bfloat162_rn(make_float2(b.x, b.y));
    u.h2[3] = __float22bfloat162_rn(make_float2(b.z, b.w));
    return u.v;
}
__device__ __forceinline__ float fsig(float x) { return 1.0f / (1.0f + __expf(-x)); }
__device__ __forceinline__ float ftanh(float x) {
    float e = __expf(2.0f * x);
    return 1.0f - 2.0f / (e + 1.0f);
}

__global__ __launch_bounds__(512)
__attribute__((amdgpu_waves_per_eu(2, 4)))
void treelstm_main(const float* __restrict__ x,
                   const float* __restrict__ Uh,
                   const float* __restrict__ fc,
                   const float* __restrict__ W_iou,
                   const float* __restrict__ b_iou,
                   const float* __restrict__ W_f,
                   const float* __restrict__ b_f,
                   float* __restrict__ out) {
    __shared__ float xlds[3][16 * XSTR];     // 49536 B
    __shared__ float blds[1024];             // 4 KB biases [i|o|u|f]

    const int tid   = threadIdx.x;
    const int lane  = tid & 63;
    const int w     = tid >> 6;              // wave 0..7
    const int q     = lane >> 4;
    const int bcol  = lane & 15;
    const int half  = blockIdx.x >> 8;       // width half (b, b+256 same XCD)
    const int phase = blockIdx.x & 255;      // row phase
    const int sl    = half * 8 + w;          // global slice 0..15
    const int kb    = sl * 16 + q * 4;       // lane's 4 output cols per gate
    const int C     = sl * 16 + bcol;        // W row for A-frag

    // ---- W fragments, loaded once (A[row=lane&15 -> col C][k=ks*32+q*8..]) ----
    bf16x8 wreg[32];
#pragma unroll
    for (int g = 0; g < 4; ++g) {
        const float* wr = (g < 3) ? (W_iou + (size_t)(g * 256 + C) * 256)
                                  : (W_f + (size_t)C * 256);
#pragma unroll
        for (int ks = 0; ks < 8; ++ks) {
            const f4v p0 = *(const f4v*)(wr + ks * 32 + q * 8);
            const f4v p1 = *(const f4v*)(wr + ks * 32 + q * 8 + 4);
            wreg[g * 8 + ks] = pack8(p0, p1);
        }
    }
    // ---- biases -> LDS (completes before VMW(0) baseline below) ----
    blds[tid]       = b_iou[tid];
    blds[512 + tid] = (tid < 256) ? b_iou[512 + tid] : b_f[tid - 256];
    VMW(0); SBR();                           // clean vmcnt baseline

    float* out_h = out;
    float* out_c = out + (size_t)N_ROWS * 256;
    float* out_f = out + 2 * (size_t)N_ROWS * 256;

    const int cnt  = (TILES - phase + 255) >> 8;   // 48 or 49 tiles
    const int trip = cnt / 3;                      // 16
    const int rem  = cnt - 3 * trip;               // 0 or 1

    auto TN = [&](int j) { const int jj = (j < cnt) ? j : (cnt - 1);
                           return phase + (jj << 8); };

    auto STAGE = [&](int t, int rb) {        // 2 x global_load_lds (16B)
#pragma unroll
        for (int rr = 0; rr < 2; ++rr) {
            const int r = 2 * w + rr;
            const float* src = x + (size_t)(t * 16 + r) * 256 + lane * 4;
            __builtin_amdgcn_global_load_lds(
                (const __attribute__((address_space(1))) uint32_t*)src,
                (__attribute__((address_space(3))) uint32_t*)&xlds[rb][r * XSTR],
                16, 0, 0);
        }
        SBR();
    };

    auto LOADUH = [&](int t, f4v& ui, f4v& uo, f4v& uu, f4v& fv) {   // 4 loads
        const float* uh = Uh + (size_t)(t * 16 + bcol) * 768 + kb;
        ui = __builtin_nontemporal_load((const f4v*)uh);
        uo = __builtin_nontemporal_load((const f4v*)(uh + 256));
        uu = __builtin_nontemporal_load((const f4v*)(uh + 512));
        fv = __builtin_nontemporal_load((const f4v*)(fc + (size_t)(t * 16 + bcol) * 256 + kb));
    };

    auto WORK = [&](int rb, int t, const f4v& ui, const f4v& uo,
                    const f4v& uu, const f4v& fv) {  // MFMA + epilogue (3 stores)
        f4v a0 = *(const f4v*)&blds[kb];             // bias init via LDS (lgkm)
        f4v a1 = *(const f4v*)&blds[256 + kb];
        f4v a2 = *(const f4v*)&blds[512 + kb];
        f4v a3 = *(const f4v*)&blds[768 + kb];
#pragma unroll
        for (int ks = 0; ks < 8; ++ks) {
            const f4v p0 = *(const f4v*)&xlds[rb][bcol * XSTR + ks * 32 + q * 8];
            const f4v p1 = *(const f4v*)&xlds[rb][bcol * XSTR + ks * 32 + q * 8 + 4];
            const bf16x8 xf = pack8(p0, p1);
            a0 = __builtin_amdgcn_mfma_f32_16x16x32_bf16(wreg[0 * 8 + ks], xf, a0, 0, 0, 0);
            a1 = __builtin_amdgcn_mfma_f32_16x16x32_bf16(wreg[1 * 8 + ks], xf, a1, 0, 0, 0);
            a2 = __builtin_amdgcn_mfma_f32_16x16x32_bf16(wreg[2 * 8 + ks], xf, a2, 0, 0, 0);
            a3 = __builtin_amdgcn_mfma_f32_16x16x32_bf16(wreg[3 * 8 + ks], xf, a3, 0, 0, 0);
        }
        const int n = t * 16 + bcol;
        f4v cc, hh, ff;
        cc.x = fsig(a0.x + ui.x) * ftanh(a2.x + uu.x) + fv.x;
        cc.y = fsig(a0.y + ui.y) * ftanh(a2.y + uu.y) + fv.y;
        cc.z = fsig(a0.z + ui.z) * ftanh(a2.z + uu.z) + fv.z;
        cc.w = fsig(a0.w + ui.w) * ftanh(a2.w + uu.w) + fv.w;
        hh.x = fsig(a1.x + uo.x) * ftanh(cc.x);
        hh.y = fsig(a1.y + uo.y) * ftanh(cc.y);
        hh.z = fsig(a1.z + uo.z) * ftanh(cc.z);
        hh.w = fsig(a1.w + uo.w) * ftanh(cc.w);
        ff.x = a3.x; ff.y = a3.y; ff.z = a3.z; ff.w = a3.w;
        const size_t oidx = (size_t)n * 256 + kb;
        *(f4v*)(out_h + oidx) = hh;
        *(f4v*)(out_c + oidx) = cc;
        *(f4v*)(out_f + oidx) = ff;
    };

    f4v uhiA, uhoA, uhuA, fcvA;     // 3 named uh sets: static, period-3
    f4v uhiB, uhoB, uhuB, fcvB;
    f4v uhiC, uhoC, uhuC, fcvC;

    // ---- prologue: stage+load tiles j=0,1 ----
    STAGE(TN(0), 0); LOADUH(TN(0), uhiA, uhoA, uhuA, fcvA);
    STAGE(TN(1), 1); LOADUH(TN(1), uhiB, uhoB, uhuB, fcvB);
    // outstanding: S0(2) A(4) S1(2) B(4) = 12 -> drain S0
    VMW(10);
    LKW0();                                  // bias ds_writes visible to all
    __builtin_amdgcn_s_barrier(); SBR();

    for (int k = 0; k < trip; ++k) {
        const int j0 = 3 * k;

        // ---- tile j0: read buf0, stage buf2 <- j0+2, load C <- j0+2 ----
        STAGE(TN(j0 + 2), 2);
        WORK(0, TN(j0), uhiA, uhoA, uhuA, fcvA);
        LOADUH(TN(j0 + 2), uhiC, uhoC, uhuC, fcvC);
        if (k == 0) { VMW(13); } else { VMW(16); }
        __builtin_amdgcn_s_barrier(); SBR();

        // ---- tile j0+1: read buf1, stage buf0 <- j0+3, load A <- j0+3 ----
        STAGE(TN(j0 + 3), 0);
        WORK(1, TN(j0 + 1), uhiB, uhoB, uhuB, fcvB);
        LOADUH(TN(j0 + 3), uhiA, uhoA, uhuA, fcvA);
        VMW(16);
        __builtin_amdgcn_s_barrier(); SBR();

        // ---- tile j0+2: read buf2, stage buf1 <- j0+4, load B <- j0+4 ----
        STAGE(TN(j0 + 4), 1);
        WORK(2, TN(j0 + 2), uhiC, uhoC, uhuC, fcvC);
        LOADUH(TN(j0 + 4), uhiB, uhoB, uhuB, fcvB);
        VMW(16);
        __builtin_amdgcn_s_barrier(); SBR();
    }

    if (rem) {      // tile 3*trip: buf index (3*trip)%3 == 0, uh set A
        WORK(0, TN(3 * trip), uhiA, uhoA, uhuA, fcvA);
    }
}

extern "C" void kernel_launch(void* const* d_in, const int* in_sizes, int n_in,
                              void* d_out, int out_size, void* d_ws, size_t ws_size,
                              hipStream_t stream) {
    const float* x     = (const float*)d_in[0];
    const float* Uh    = (const float*)d_in[1];
    const float* fc    = (const float*)d_in[2];
    const float* W_iou = (const float*)d_in[3];
    const float* b_iou = (const float*)d_in[4];
    const float* W_f   = (const float*)d_in[5];
    const float* b_f   = (const float*)d_in[6];
    float* out = (float*)d_out;

    treelstm_main<<<512, 512, 0, stream>>>(x, Uh, fc, W_iou, b_iou, W_f, b_f, out);
}

// Round 19
// 383.181 us; speedup vs baseline: 1.1726x; 1.1726x over previous
//
#include <hip/hip_runtime.h>
#include <hip/hip_bf16.h>
#include <stdint.h>

// TreeLSTM fused, round 19: barrier amortization (1 per 3 tiles) + wave skew.
// R14-18 analysis: all pipes <=35% busy, loads always prefetched -> the cost
// is lockstep convoys at the per-tile barrier. Ring-of-6 LDS (99 KB), groups
// of 3 tiles: issue 12 uh loads + 6 next-group stages up front (uh older than
// stages -> compiler's uh waits never drain stages), 3 WORKs barrier-free,
// then vmcnt(9) (drains stages, leaves 9 stores) + one barrier.
// Grid 256 (128 phases x 2 XCD-paired halves), 8 waves, VGPR budget 256 via
// waves_per_eu(2,2). W fragments + biases register-resident.

typedef __attribute__((ext_vector_type(8))) short bf16x8;
typedef __attribute__((ext_vector_type(4))) float f4v;

#define N_ROWS 200000
#define TILES 12500     // N_ROWS / 16
#define XSTR 258        // LDS row stride in floats -> 0 bank conflicts (R14)
#define VMW(N) asm volatile("s_waitcnt vmcnt(" #N ")" ::: "memory")
#define SBR() __builtin_amdgcn_sched_barrier(0)

__device__ __forceinline__ bf16x8 pack8(f4v a, f4v b) {
    union { __hip_bfloat162 h2[4]; bf16x8 v; } u;
    u.h2[0] = __float22bfloat162_rn(make_float2(a.x, a.y));
    u.h2[1] = __float22bfloat162_rn(make_float2(a.z, a.w));
    u.h2[2] = __float22bfloat162_rn(make_float2(b.x, b.y));
    u.h2[3] = __float22bfloat162_rn(make_float2(b.z, b.w));
    return u.v;
}
__device__ __forceinline__ float fsig(float x) { return 1.0f / (1.0f + __expf(-x)); }
__device__ __forceinline__ float ftanh(float x) {
    float e = __expf(2.0f * x);
    return 1.0f - 2.0f / (e + 1.0f);
}

__global__ __launch_bounds__(512)
__attribute__((amdgpu_waves_per_eu(2, 2)))
void treelstm_main(const float* __restrict__ x,
                   const float* __restrict__ Uh,
                   const float* __restrict__ fc,
                   const float* __restrict__ W_iou,
                   const float* __restrict__ b_iou,
                   const float* __restrict__ W_f,
                   const float* __restrict__ b_f,
                   float* __restrict__ out) {
    __shared__ float xlds[6][16 * XSTR];     // 99072 B, ring of 6

    const int tid   = threadIdx.x;
    const int lane  = tid & 63;
    const int w     = tid >> 6;              // wave 0..7
    const int q     = lane >> 4;
    const int bcol  = lane & 15;
    const int half  = blockIdx.x >> 7;       // width half (b, b+128 same XCD)
    const int phase = blockIdx.x & 127;      // row phase
    const int sl    = half * 8 + w;          // global slice 0..15
    const int kb    = sl * 16 + q * 4;       // lane's 4 output cols per gate
    const int C     = sl * 16 + bcol;        // W row for A-frag

    // ---- resident biases ----
    const f4v bI = *(const f4v*)&b_iou[kb];
    const f4v bO = *(const f4v*)&b_iou[256 + kb];
    const f4v bU = *(const f4v*)&b_iou[512 + kb];
    const f4v bF = *(const f4v*)&b_f[kb];

    // ---- W fragments, loaded once (A[row=lane&15 -> col C][k=ks*32+q*8..]) ----
    bf16x8 wreg[32];
#pragma unroll
    for (int g = 0; g < 4; ++g) {
        const float* wr = (g < 3) ? (W_iou + (size_t)(g * 256 + C) * 256)
                                  : (W_f + (size_t)C * 256);
#pragma unroll
        for (int ks = 0; ks < 8; ++ks) {
            const f4v p0 = *(const f4v*)(wr + ks * 32 + q * 8);
            const f4v p1 = *(const f4v*)(wr + ks * 32 + q * 8 + 4);
            wreg[g * 8 + ks] = pack8(p0, p1);
        }
    }

    float* out_h = out;
    float* out_c = out + (size_t)N_ROWS * 256;
    float* out_f = out + 2 * (size_t)N_ROWS * 256;

    const int cnt = (TILES - phase + 127) >> 7;    // 97 or 98
    const int G   = cnt / 3;                       // 32 full groups
    const int rem = cnt - 3 * G;                   // 1 or 2 tail tiles

    auto TN = [&](int j) { const int jj = (j < cnt) ? j : (cnt - 1);
                           return phase + (jj << 7); };

    auto STAGE = [&](int t, int rb) {        // 2 x global_load_lds (16B)
#pragma unroll
        for (int rr = 0; rr < 2; ++rr) {
            const int r = 2 * w + rr;
            const float* src = x + (size_t)(t * 16 + r) * 256 + lane * 4;
            __builtin_amdgcn_global_load_lds(
                (const __attribute__((address_space(1))) uint32_t*)src,
                (__attribute__((address_space(3))) uint32_t*)&xlds[rb][r * XSTR],
                16, 0, 0);
        }
    };

    auto LOADUH = [&](int t, f4v& ui, f4v& uo, f4v& uu, f4v& fv) {   // 4 loads
        const float* uh = Uh + (size_t)(t * 16 + bcol) * 768 + kb;
        ui = __builtin_nontemporal_load((const f4v*)uh);
        uo = __builtin_nontemporal_load((const f4v*)(uh + 256));
        uu = __builtin_nontemporal_load((const f4v*)(uh + 512));
        fv = __builtin_nontemporal_load((const f4v*)(fc + (size_t)(t * 16 + bcol) * 256 + kb));
    };

    auto WORK = [&](int rb, int t, const f4v& ui, const f4v& uo,
                    const f4v& uu, const f4v& fv) {  // MFMA + epilogue (3 stores)
        f4v a0 = bI, a1 = bO, a2 = bU, a3 = bF;
#pragma unroll
        for (int ks = 0; ks < 8; ++ks) {
            const f4v p0 = *(const f4v*)&xlds[rb][bcol * XSTR + ks * 32 + q * 8];
            const f4v p1 = *(const f4v*)&xlds[rb][bcol * XSTR + ks * 32 + q * 8 + 4];
            const bf16x8 xf = pack8(p0, p1);
            a0 = __builtin_amdgcn_mfma_f32_16x16x32_bf16(wreg[0 * 8 + ks], xf, a0, 0, 0, 0);
            a1 = __builtin_amdgcn_mfma_f32_16x16x32_bf16(wreg[1 * 8 + ks], xf, a1, 0, 0, 0);
            a2 = __builtin_amdgcn_mfma_f32_16x16x32_bf16(wreg[2 * 8 + ks], xf, a2, 0, 0, 0);
            a3 = __builtin_amdgcn_mfma_f32_16x16x32_bf16(wreg[3 * 8 + ks], xf, a3, 0, 0, 0);
        }
        const int n = t * 16 + bcol;
        f4v cc, hh, ff;
        cc.x = fsig(a0.x + ui.x) * ftanh(a2.x + uu.x) + fv.x;
        cc.y = fsig(a0.y + ui.y) * ftanh(a2.y + uu.y) + fv.y;
        cc.z = fsig(a0.z + ui.z) * ftanh(a2.z + uu.z) + fv.z;
        cc.w = fsig(a0.w + ui.w) * ftanh(a2.w + uu.w) + fv.w;
        hh.x = fsig(a1.x + uo.x) * ftanh(cc.x);
        hh.y = fsig(a1.y + uo.y) * ftanh(cc.y);
        hh.z = fsig(a1.z + uo.z) * ftanh(cc.z);
        hh.w = fsig(a1.w + uo.w) * ftanh(cc.w);
        ff.x = a3.x; ff.y = a3.y; ff.z = a3.z; ff.w = a3.w;
        const size_t oidx = (size_t)n * 256 + kb;
        *(f4v*)(out_h + oidx) = hh;
        *(f4v*)(out_c + oidx) = cc;
        *(f4v*)(out_f + oidx) = ff;
    };

    f4v ui0, uo0, uu0, fv0, ui1, uo1, uu1, fv1, ui2, uo2, uu2, fv2;

    // ---- prologue: stage group 0 (bufs 0..2) ----
    STAGE(TN(0), 0); STAGE(TN(1), 1); STAGE(TN(2), 2);
    VMW(0);
    __builtin_amdgcn_s_barrier(); SBR();

    for (int g = 0; g < G; ++g) {
        const int j0 = 3 * g;
        const int rB = (g & 1) * 3;          // read bufs rB..rB+2
        const int sB = 3 - rB;               // stage bufs for group g+1

        // ---- issue: uh for this group's 3 tiles (oldest), then stages ----
        LOADUH(TN(j0),     ui0, uo0, uu0, fv0);
        LOADUH(TN(j0 + 1), ui1, uo1, uu1, fv1);
        LOADUH(TN(j0 + 2), ui2, uo2, uu2, fv2);
        SBR();
        STAGE(TN(j0 + 3), sB); STAGE(TN(j0 + 4), sB + 1); STAGE(TN(j0 + 5), sB + 2);
        SBR();

        // ---- 3 tiles, no barriers between: waves skew freely ----
        WORK(rB,     TN(j0),     ui0, uo0, uu0, fv0);
        WORK(rB + 1, TN(j0 + 1), ui1, uo1, uu1, fv1);
        WORK(rB + 2, TN(j0 + 2), ui2, uo2, uu2, fv2);

        // drain the 6 stages (youngest except our 9 stores); stores fly on
        VMW(9);
        __builtin_amdgcn_s_barrier(); SBR();
    }

    // ---- tail: 1 or 2 tiles; bufs (G&1)*3 + j, staged by group G-1 ----
    const int tb = (G & 1) * 3;
    for (int j = 0; j < rem; ++j) {
        LOADUH(TN(3 * G + j), ui0, uo0, uu0, fv0);
        WORK(tb + j, TN(3 * G + j), ui0, uo0, uu0, fv0);
    }
}

extern "C" void kernel_launch(void* const* d_in, const int* in_sizes, int n_in,
                              void* d_out, int out_size, void* d_ws, size_t ws_size,
                              hipStream_t stream) {
    const float* x     = (const float*)d_in[0];
    const float* Uh    = (const float*)d_in[1];
    const float* fc    = (const float*)d_in[2];
    const float* W_iou = (const float*)d_in[3];
    const float* b_iou = (const float*)d_in[4];
    const float* W_f   = (const float*)d_in[5];
    const float* b_f   = (const float*)d_in[6];
    float* out = (float*)d_out;

    treelstm_main<<<256, 512, 0, stream>>>(x, Uh, fc, W_iou, b_iou, W_f, b_f, out);
}